// Round 9
// baseline (570.239 us; speedup 1.0000x reference)
//
#include <hip/hip_runtime.h>
#include <hip/hip_bf16.h>

// Problem constants: B=2, T=2048, D=1024, H=16, G=4, K=64, F=4096
#define EPSF 1e-6f
constexpr int Bsz  = 2;
constexpr int Tseq = 2048;
constexpr int Dmod = 1024;
constexpr int Hh   = 16;
constexpr int Gg   = 4;
constexpr int Ff   = 4096;
constexpr int Mrows = Bsz * Tseq;          // 4096 tokens

typedef __attribute__((ext_vector_type(8))) short bf16x8;   // 8 bf16 (4 VGPRs)
typedef __attribute__((ext_vector_type(4))) float f32x4;
typedef unsigned short u16;

// RNE fp32 -> bf16 (bit pattern as u16)
__device__ inline u16 f2bf(float x) {
    union { float f; unsigned u; } v; v.f = x;
    unsigned r = v.u + 0x7fff + ((v.u >> 16) & 1);
    return (u16)(r >> 16);
}
__device__ inline float bf2f(u16 h) {
    union { unsigned u; float f; } v; v.u = ((unsigned)h) << 16; return v.f;
}

// Async global->LDS DMA, 16 B per lane (wave-uniform base + lane*16).
__device__ __forceinline__ void async_copy16(const u16* g, u16* l) {
    __builtin_amdgcn_global_load_lds(
        (const __attribute__((address_space(1))) void*)g,
        (__attribute__((address_space(3))) void*)l, 16, 0, 0);
}

// Bank-swizzle: LDS tiles [row][32] bf16 (64 B rows). Logical k-chunk q of row
// R stored at chunk q ^ ((R>>1)&3); staging fetches global chunk
// (lane&3)^((row>>1)&3) into linear dest lane*16; reads XOR the same term.
// -> 2-way (free) instead of 8-way conflicts (verified r7: conflicts = 0).

// ---------------------------------------------------------------------------
// ALL weight prep in ONE launch. Each block transposes one 32x32 fp32 tile to
// bf16 (o_w also emits lo residual). Flattened grid, 14848 blocks:
//   [0,1024) q | [1024,1280) k | [1280,1536) v | [1536,2560) o (hi+lo)
//   [2560,6656) gate | [6656,10752) up | [10752,14848) down
// ---------------------------------------------------------------------------
__global__ __launch_bounds__(256) void wprep_all_kernel(
    const float* __restrict__ q_w, const float* __restrict__ k_w,
    const float* __restrict__ v_w, const float* __restrict__ o_w,
    const float* __restrict__ gate_w, const float* __restrict__ up_w,
    const float* __restrict__ down_w,
    u16* __restrict__ QKVT, u16* __restrict__ OTh, u16* __restrict__ OTl,
    u16* __restrict__ GTh, u16* __restrict__ UTh, u16* __restrict__ DTh)
{
    const int bx = blockIdx.x;
    const float* W; u16* Th; u16* Tl = nullptr;
    int N, Kd, ntile, ktile, drow;
    if (bx < 1024) {
        W = q_w; N = 1024; Kd = 1024; ntile = bx & 31; ktile = bx >> 5;
        Th = QKVT; drow = ntile * 32;
    } else if (bx < 1280) {
        const int i = bx - 1024;
        W = k_w; N = 256; Kd = 1024; ntile = i & 7; ktile = i >> 3;
        Th = QKVT; drow = 1024 + ntile * 32;
    } else if (bx < 1536) {
        const int i = bx - 1280;
        W = v_w; N = 256; Kd = 1024; ntile = i & 7; ktile = i >> 3;
        Th = QKVT; drow = 1280 + ntile * 32;
    } else if (bx < 2560) {
        const int i = bx - 1536;
        W = o_w; N = 1024; Kd = 1024; ntile = i & 31; ktile = i >> 5;
        Th = OTh; Tl = OTl; drow = ntile * 32;
    } else if (bx < 6656) {
        const int i = bx - 2560;
        W = gate_w; N = 4096; Kd = 1024; ntile = i & 127; ktile = i >> 7;
        Th = GTh; drow = ntile * 32;
    } else if (bx < 10752) {
        const int i = bx - 6656;
        W = up_w; N = 4096; Kd = 1024; ntile = i & 127; ktile = i >> 7;
        Th = UTh; drow = ntile * 32;
    } else {
        const int i = bx - 10752;
        W = down_w; N = 1024; Kd = 4096; ntile = i & 31; ktile = i >> 5;
        Th = DTh; drow = ntile * 32;
    }
    const int n0 = ntile * 32, k0 = ktile * 32;

    __shared__ float tile[32][33];
    const int r = threadIdx.x >> 3, c4 = (threadIdx.x & 7) * 4;
    const float4 v = *reinterpret_cast<const float4*>(&W[(size_t)(k0 + r) * N + n0 + c4]);
    tile[r][c4 + 0] = v.x; tile[r][c4 + 1] = v.y;
    tile[r][c4 + 2] = v.z; tile[r][c4 + 3] = v.w;
    __syncthreads();
    const int nl = threadIdx.x >> 3, kq = (threadIdx.x & 7) * 4;
    float x0 = tile[kq + 0][nl], x1 = tile[kq + 1][nl];
    float x2 = tile[kq + 2][nl], x3 = tile[kq + 3][nl];
    ushort4 h;
    h.x = f2bf(x0); h.y = f2bf(x1); h.z = f2bf(x2); h.w = f2bf(x3);
    *reinterpret_cast<ushort4*>(&Th[(size_t)(drow + nl) * Kd + k0 + kq]) = h;
    if (Tl) {
        ushort4 l;
        l.x = f2bf(x0 - bf2f(h.x)); l.y = f2bf(x1 - bf2f(h.y));
        l.z = f2bf(x2 - bf2f(h.z)); l.w = f2bf(x3 - bf2f(h.w));
        *reinterpret_cast<ushort4*>(&Tl[(size_t)(drow + nl) * Kd + k0 + kq]) = l;
    }
}

// ---------------------------------------------------------------------------
// RMSNorm over D=1024 -> bf16 hi (+ optional lo). One block per token.
// ---------------------------------------------------------------------------
template <int LO>
__global__ __launch_bounds__(256) void rmsnorm_split_kernel(
    const float* __restrict__ x, const float* __restrict__ scale,
    u16* __restrict__ oh, u16* __restrict__ ol)
{
    const int row = blockIdx.x;
    const int tid = threadIdx.x;
    const float4 v = reinterpret_cast<const float4*>(x + (size_t)row * Dmod)[tid];
    float ss = v.x * v.x + v.y * v.y + v.z * v.z + v.w * v.w;
    #pragma unroll
    for (int off = 32; off; off >>= 1) ss += __shfl_xor(ss, off, 64);
    __shared__ float part[4];
    if ((tid & 63) == 0) part[tid >> 6] = ss;
    __syncthreads();
    const float tot = part[0] + part[1] + part[2] + part[3];
    const float rstd = rsqrtf(tot * (1.0f / Dmod) + EPSF);
    const float4 sc = reinterpret_cast<const float4*>(scale)[tid];
    float o0 = v.x * rstd * sc.x, o1 = v.y * rstd * sc.y;
    float o2 = v.z * rstd * sc.z, o3 = v.w * rstd * sc.w;
    ushort4 h;
    h.x = f2bf(o0); h.y = f2bf(o1); h.z = f2bf(o2); h.w = f2bf(o3);
    *reinterpret_cast<ushort4*>(&oh[(size_t)row * Dmod + tid * 4]) = h;
    if (LO) {
        ushort4 l;
        l.x = f2bf(o0 - bf2f(h.x)); l.y = f2bf(o1 - bf2f(h.y));
        l.z = f2bf(o2 - bf2f(h.z)); l.w = f2bf(o3 - bf2f(h.w));
        *reinterpret_cast<ushort4*>(&ol[(size_t)row * Dmod + tid * 4]) = l;
    }
}

// ---------------------------------------------------------------------------
// Split-bf16 MFMA GEMM, async DMA + swizzle (unchanged from r7).
// ---------------------------------------------------------------------------
template <int ASPLIT, int BSPLIT, int RES>
__global__ __launch_bounds__(256, 2) void mfma_gemm_kernel(
    const u16* __restrict__ Ah, const u16* __restrict__ Al,
    const u16* __restrict__ Bh, const u16* __restrict__ Bl,
    const float* __restrict__ res, float* __restrict__ C,
    int M, int N, int Kd)
{
    __shared__ u16 As_h[128 * 32];
    __shared__ u16 As_l[128 * 32];
    __shared__ u16 Bs_h[128 * 32];
    __shared__ u16 Bs_l[128 * 32];

    const int tid = threadIdx.x;
    const int lane = tid & 63, wave = tid >> 6;
    const int wm = (wave >> 1) * 64, wn = (wave & 1) * 64;
    const int m0 = blockIdx.y * 128, n0 = blockIdx.x * 128;
    const int fm = lane & 15, quad = lane >> 4;
    const int fsw = (fm >> 1) & 3;
    const int fcol = ((quad ^ fsw) * 8);

    f32x4 acc[4][4];
    #pragma unroll
    for (int i = 0; i < 4; ++i)
        #pragma unroll
        for (int j = 0; j < 4; ++j) acc[i][j] = (f32x4){0.f, 0.f, 0.f, 0.f};

    const int lrow = lane >> 2;
    const int lchunk = lane & 3;
    const int schunk = lchunk ^ ((lrow >> 1) & 3);

    for (int k0 = 0; k0 < Kd; k0 += 32) {
        __syncthreads();
        #pragma unroll
        for (int p = 0; p < 2; ++p) {
            const int row = wave * 32 + p * 16 + lrow;
            const size_t ga = (size_t)(m0 + row) * Kd + k0 + schunk * 8;
            const size_t gb = (size_t)(n0 + row) * Kd + k0 + schunk * 8;
            const int ls = row * 32 + lchunk * 8;
            async_copy16(&Ah[ga], &As_h[ls]);
            if (ASPLIT) async_copy16(&Al[ga], &As_l[ls]);
            async_copy16(&Bh[gb], &Bs_h[ls]);
            if (BSPLIT) async_copy16(&Bl[gb], &Bs_l[ls]);
        }
        __syncthreads();

        bf16x8 ah[4], al[4], bh[4], bl[4];
        #pragma unroll
        for (int t = 0; t < 4; ++t) {
            const int ra = (wm + t * 16 + fm) * 32 + fcol;
            const int rb = (wn + t * 16 + fm) * 32 + fcol;
            ah[t] = *reinterpret_cast<const bf16x8*>(&As_h[ra]);
            bh[t] = *reinterpret_cast<const bf16x8*>(&Bs_h[rb]);
            if (ASPLIT) al[t] = *reinterpret_cast<const bf16x8*>(&As_l[ra]);
            if (BSPLIT) bl[t] = *reinterpret_cast<const bf16x8*>(&Bs_l[rb]);
        }
        #pragma unroll
        for (int mt = 0; mt < 4; ++mt)
            #pragma unroll
            for (int nt = 0; nt < 4; ++nt) {
                acc[mt][nt] = __builtin_amdgcn_mfma_f32_16x16x32_bf16(
                    ah[mt], bh[nt], acc[mt][nt], 0, 0, 0);
                if (BSPLIT)
                    acc[mt][nt] = __builtin_amdgcn_mfma_f32_16x16x32_bf16(
                        ah[mt], bl[nt], acc[mt][nt], 0, 0, 0);
                if (ASPLIT)
                    acc[mt][nt] = __builtin_amdgcn_mfma_f32_16x16x32_bf16(
                        al[mt], bh[nt], acc[mt][nt], 0, 0, 0);
            }
    }

    const int cr = (lane >> 4) * 4, cn = lane & 15;
    #pragma unroll
    for (int mt = 0; mt < 4; ++mt)
        #pragma unroll
        for (int nt = 0; nt < 4; ++nt)
            #pragma unroll
            for (int r = 0; r < 4; ++r) {
                const int gm = m0 + wm + mt * 16 + cr + r;
                const int gn = n0 + wn + nt * 16 + cn;
                float v = acc[mt][nt][r];
                if (RES) v += res[(size_t)gm * N + gn];
                C[(size_t)gm * N + gn] = v;
            }
}

// ---------------------------------------------------------------------------
// Fused QKV GEMM + qk-norm + RoPE + bf16 split epilogue; V stored TRANSPOSED
// directly (Vt[(b*4+g)*64+d][t]) -- the 4 r-values of a C reg are 4
// consecutive t's in one lane -> ushort4 stores. No separate vtrans pass.
// ---------------------------------------------------------------------------
__global__ __launch_bounds__(256, 2) void qkv_fused_kernel(
    const u16* __restrict__ Ah, const u16* __restrict__ Bh,
    const float* __restrict__ qn, const float* __restrict__ kn,
    const float* __restrict__ sinp, const float* __restrict__ cosp,
    u16* __restrict__ Qbh, u16* __restrict__ Qbl,
    u16* __restrict__ Kbh, u16* __restrict__ Kbl,
    u16* __restrict__ Vth, u16* __restrict__ Vtl)
{
    __shared__ u16 As_h[128 * 32];
    __shared__ u16 Bs_h[128 * 32];

    const int Kd = 1024;
    const int tid = threadIdx.x;
    const int lane = tid & 63, wave = tid >> 6;
    const int wm = (wave >> 1) * 64, wn = (wave & 1) * 64;
    const int m0 = blockIdx.y * 128, n0 = blockIdx.x * 128;
    const int fm = lane & 15, quad = lane >> 4;
    const int fsw = (fm >> 1) & 3;
    const int fcol = ((quad ^ fsw) * 8);

    f32x4 acc[4][4];
    #pragma unroll
    for (int i = 0; i < 4; ++i)
        #pragma unroll
        for (int j = 0; j < 4; ++j) acc[i][j] = (f32x4){0.f, 0.f, 0.f, 0.f};

    const int lrow = lane >> 2;
    const int lchunk = lane & 3;
    const int schunk = lchunk ^ ((lrow >> 1) & 3);

    for (int k0 = 0; k0 < Kd; k0 += 32) {
        __syncthreads();
        #pragma unroll
        for (int p = 0; p < 2; ++p) {
            const int row = wave * 32 + p * 16 + lrow;
            const size_t ga = (size_t)(m0 + row) * Kd + k0 + schunk * 8;
            const size_t gb = (size_t)(n0 + row) * Kd + k0 + schunk * 8;
            const int ls = row * 32 + lchunk * 8;
            async_copy16(&Ah[ga], &As_h[ls]);
            async_copy16(&Bh[gb], &Bs_h[ls]);
        }
        __syncthreads();

        bf16x8 ah[4], bh[4];
        #pragma unroll
        for (int t = 0; t < 4; ++t) {
            ah[t] = *reinterpret_cast<const bf16x8*>(&As_h[(wm + t * 16 + fm) * 32 + fcol]);
            bh[t] = *reinterpret_cast<const bf16x8*>(&Bs_h[(wn + t * 16 + fm) * 32 + fcol]);
        }
        #pragma unroll
        for (int mt = 0; mt < 4; ++mt)
            #pragma unroll
            for (int nt = 0; nt < 4; ++nt)
                acc[mt][nt] = __builtin_amdgcn_mfma_f32_16x16x32_bf16(
                    ah[mt], bh[nt], acc[mt][nt], 0, 0, 0);
    }

    const int gn0 = n0 + wn;          // wave col base, 64-aligned
    const int l15 = lane & 15;

    if (gn0 < 1280) {
        // ---- Q or K: per-head RMSNorm + RoPE + split ----
        const bool isQ = (gn0 < 1024);
        const float* nsc = isQ ? qn : kn;
        const float osc = isQ ? 0.125f : 1.0f;
        u16* __restrict__ oh = isQ ? Qbh : Kbh;
        u16* __restrict__ ol = isQ ? Qbl : Kbl;
        const int rowstride = isQ ? 1024 : 256;
        const int colbase = isQ ? gn0 : gn0 - 1024;
        float sc[4];
        #pragma unroll
        for (int nt = 0; nt < 4; ++nt) sc[nt] = nsc[nt * 16 + l15];

        #pragma unroll
        for (int mt = 0; mt < 4; ++mt)
            #pragma unroll
            for (int r = 0; r < 4; ++r) {
                const int bt = m0 + wm + mt * 16 + quad * 4 + r;
                float v[4];
                #pragma unroll
                for (int nt = 0; nt < 4; ++nt) v[nt] = acc[mt][nt][r];
                float ss = v[0] * v[0] + v[1] * v[1] + v[2] * v[2] + v[3] * v[3];
                #pragma unroll
                for (int off = 1; off < 16; off <<= 1)
                    ss += __shfl_xor(ss, off, 16);
                const float rstd = rsqrtf(ss * (1.0f / 64.0f) + EPSF);
                float nv[4];
                #pragma unroll
                for (int nt = 0; nt < 4; ++nt) nv[nt] = v[nt] * rstd * sc[nt];
                const float s0 = sinp[bt * 32 + l15];
                const float c0 = cosp[bt * 32 + l15];
                const float s1 = sinp[bt * 32 + 16 + l15];
                const float c1 = cosp[bt * 32 + 16 + l15];
                float o[4];
                o[0] = (nv[0] * c0 - nv[2] * s0) * osc;
                o[1] = (nv[1] * c1 - nv[3] * s1) * osc;
                o[2] = (nv[2] * c0 + nv[0] * s0) * osc;
                o[3] = (nv[3] * c1 + nv[1] * s1) * osc;
                #pragma unroll
                for (int nt = 0; nt < 4; ++nt) {
                    const size_t off = (size_t)bt * rowstride + colbase + nt * 16 + l15;
                    const u16 hi = f2bf(o[nt]);
                    oh[off] = hi;
                    ol[off] = f2bf(o[nt] - bf2f(hi));
                }
            }
    } else {
        // ---- V: bf16 split, stored transposed: Vt[(b*4+g)*64+d][t] ----
        const int g = (gn0 - 1280) >> 6;
        const int b = (m0 + wm) >> 11;
        const int tb = ((m0 + wm) & 2047) + quad * 4;
        #pragma unroll
        for (int mt = 0; mt < 4; ++mt)
            #pragma unroll
            for (int nt = 0; nt < 4; ++nt) {
                const float v0 = acc[mt][nt][0], v1 = acc[mt][nt][1];
                const float v2 = acc[mt][nt][2], v3 = acc[mt][nt][3];
                ushort4 hv, lv;
                hv.x = f2bf(v0); hv.y = f2bf(v1); hv.z = f2bf(v2); hv.w = f2bf(v3);
                lv.x = f2bf(v0 - bf2f(hv.x)); lv.y = f2bf(v1 - bf2f(hv.y));
                lv.z = f2bf(v2 - bf2f(hv.z)); lv.w = f2bf(v3 - bf2f(hv.w));
                const size_t off =
                    ((size_t)((b * 4 + g) * 64 + nt * 16 + l15)) * Tseq + tb + mt * 16;
                *reinterpret_cast<ushort4*>(&Vth[off]) = hv;
                *reinterpret_cast<ushort4*>(&Vtl[off]) = lv;
            }
    }
}

// ---------------------------------------------------------------------------
// Fused gate/up MFMA GEMM + silu epilogue (unchanged from r7).
// ---------------------------------------------------------------------------
__global__ __launch_bounds__(256, 2) void mfma_gateup_kernel(
    const u16* __restrict__ Ah, const u16* __restrict__ Al,
    const u16* __restrict__ Bg, const u16* __restrict__ Bu,
    u16* __restrict__ FF, int M, int N, int Kd)
{
    __shared__ u16 As_h[128 * 32];
    __shared__ u16 As_l[128 * 32];
    __shared__ u16 Gs[64 * 32];
    __shared__ u16 Us[64 * 32];

    const int tid = threadIdx.x;
    const int lane = tid & 63, wave = tid >> 6;
    const int wm = (wave >> 1) * 64, wn = (wave & 1) * 32;
    const int m0 = blockIdx.y * 128, n0 = blockIdx.x * 64;
    const int fm = lane & 15, quad = lane >> 4;
    const int fsw = (fm >> 1) & 3;
    const int fcol = ((quad ^ fsw) * 8);

    f32x4 accg[4][2], accu[4][2];
    #pragma unroll
    for (int i = 0; i < 4; ++i)
        #pragma unroll
        for (int j = 0; j < 2; ++j) {
            accg[i][j] = (f32x4){0.f, 0.f, 0.f, 0.f};
            accu[i][j] = (f32x4){0.f, 0.f, 0.f, 0.f};
        }

    const int lrow = lane >> 2;
    const int lchunk = lane & 3;
    const int schunk = lchunk ^ ((lrow >> 1) & 3);

    for (int k0 = 0; k0 < Kd; k0 += 32) {
        __syncthreads();
        #pragma unroll
        for (int p = 0; p < 2; ++p) {
            const int row = p * 64 + wave * 16 + lrow;
            const size_t ga = (size_t)(m0 + row) * Kd + k0 + schunk * 8;
            const int ls = row * 32 + lchunk * 8;
            async_copy16(&Ah[ga], &As_h[ls]);
            async_copy16(&Al[ga], &As_l[ls]);
        }
        {
            const int row = wave * 16 + lrow;
            const size_t gb = (size_t)(n0 + row) * Kd + k0 + schunk * 8;
            const int ls = row * 32 + lchunk * 8;
            async_copy16(&Bg[gb], &Gs[ls]);
            async_copy16(&Bu[gb], &Us[ls]);
        }
        __syncthreads();

        bf16x8 a_h[4], a_l[4], g_f[2], u_f[2];
        #pragma unroll
        for (int t = 0; t < 4; ++t) {
            const int ra = (wm + t * 16 + fm) * 32 + fcol;
            a_h[t] = *reinterpret_cast<const bf16x8*>(&As_h[ra]);
            a_l[t] = *reinterpret_cast<const bf16x8*>(&As_l[ra]);
        }
        #pragma unroll
        for (int j = 0; j < 2; ++j) {
            const int rb = (wn + j * 16 + fm) * 32 + fcol;
            g_f[j] = *reinterpret_cast<const bf16x8*>(&Gs[rb]);
            u_f[j] = *reinterpret_cast<const bf16x8*>(&Us[rb]);
        }
        #pragma unroll
        for (int mt = 0; mt < 4; ++mt)
            #pragma unroll
            for (int nt = 0; nt < 2; ++nt) {
                accg[mt][nt] = __builtin_amdgcn_mfma_f32_16x16x32_bf16(
                    a_h[mt], g_f[nt], accg[mt][nt], 0, 0, 0);
                accg[mt][nt] = __builtin_amdgcn_mfma_f32_16x16x32_bf16(
                    a_l[mt], g_f[nt], accg[mt][nt], 0, 0, 0);
                accu[mt][nt] = __builtin_amdgcn_mfma_f32_16x16x32_bf16(
                    a_h[mt], u_f[nt], accu[mt][nt], 0, 0, 0);
                accu[mt][nt] = __builtin_amdgcn_mfma_f32_16x16x32_bf16(
                    a_l[mt], u_f[nt], accu[mt][nt], 0, 0, 0);
            }
    }

    const int cr = (lane >> 4) * 4, cn = lane & 15;
    #pragma unroll
    for (int mt = 0; mt < 4; ++mt)
        #pragma unroll
        for (int nt = 0; nt < 2; ++nt)
            #pragma unroll
            for (int r = 0; r < 4; ++r) {
                const int gm = m0 + wm + mt * 16 + cr + r;
                const int gn = n0 + wn + nt * 16 + cn;
                const float g = accg[mt][nt][r];
                const float ff = (g / (1.0f + __expf(-g))) * accu[mt][nt][r];
                FF[(size_t)gm * N + gn] = f2bf(ff);
            }
}

// ---------------------------------------------------------------------------
// Attention strip step: S (3-chain split) -> online softmax -> PV (2-chain).
// Wave-private Ps; caller guarantees Ks/Vs are valid.
// ---------------------------------------------------------------------------
__device__ __forceinline__ void attn_strip_step(
    const bf16x8* qh, const bf16x8* ql,
    const u16* KsH, const u16* KsL, const u16* VsH, const u16* VsL,
    u16* psw, int s0, int t0, int l15, int quad,
    f32x4* oacc, float* m_r, float* l_r)
{
    f32x4 sacc[4];
    #pragma unroll
    for (int nt = 0; nt < 4; ++nt) sacc[nt] = (f32x4){0.f, 0.f, 0.f, 0.f};

    #pragma unroll
    for (int ks = 0; ks < 2; ++ks) {
        bf16x8 kfh[4], kfl[4];
        #pragma unroll
        for (int nt = 0; nt < 4; ++nt) {
            const int a = (nt * 16 + l15) * 72 + ks * 32 + quad * 8;
            kfh[nt] = *reinterpret_cast<const bf16x8*>(&KsH[a]);
            kfl[nt] = *reinterpret_cast<const bf16x8*>(&KsL[a]);
        }
        #pragma unroll
        for (int nt = 0; nt < 4; ++nt) {
            sacc[nt] = __builtin_amdgcn_mfma_f32_16x16x32_bf16(qh[ks], kfh[nt], sacc[nt], 0, 0, 0);
            sacc[nt] = __builtin_amdgcn_mfma_f32_16x16x32_bf16(ql[ks], kfh[nt], sacc[nt], 0, 0, 0);
            sacc[nt] = __builtin_amdgcn_mfma_f32_16x16x32_bf16(qh[ks], kfl[nt], sacc[nt], 0, 0, 0);
        }
    }

    if (s0 + 63 > t0) {   // diagonal tile: per-element causal mask
        #pragma unroll
        for (int nt = 0; nt < 4; ++nt) {
            const int sg = s0 + nt * 16 + l15;
            #pragma unroll
            for (int r = 0; r < 4; ++r)
                if (sg > t0 + quad * 4 + r) sacc[nt][r] = -1e30f;
        }
    }

    #pragma unroll
    for (int r = 0; r < 4; ++r) {
        float mx = fmaxf(fmaxf(sacc[0][r], sacc[1][r]),
                         fmaxf(sacc[2][r], sacc[3][r]));
        #pragma unroll
        for (int off = 1; off < 16; off <<= 1)
            mx = fmaxf(mx, __shfl_xor(mx, off, 16));
        const float mnew = fmaxf(m_r[r], mx);
        const float alpha = __expf(m_r[r] - mnew);
        m_r[r] = mnew;

        float rs = 0.0f;
        #pragma unroll
        for (int nt = 0; nt < 4; ++nt) {
            const float p = __expf(sacc[nt][r] - mnew);
            sacc[nt][r] = p;
            rs += p;
        }
        #pragma unroll
        for (int off = 1; off < 16; off <<= 1)
            rs += __shfl_xor(rs, off, 16);
        l_r[r] = l_r[r] * alpha + rs;
        #pragma unroll
        for (int nt = 0; nt < 4; ++nt) oacc[nt][r] *= alpha;
        #pragma unroll
        for (int nt = 0; nt < 4; ++nt)
            psw[(quad * 4 + r) * 72 + nt * 16 + l15] = f2bf(sacc[nt][r]);
    }
    // wave-private P: compiler lgkmcnt ordering suffices, no barrier.

    #pragma unroll
    for (int ks = 0; ks < 2; ++ks) {
        const bf16x8 pa = *reinterpret_cast<const bf16x8*>(
            &psw[l15 * 72 + ks * 32 + quad * 8]);
        bf16x8 vfh[4], vfl[4];
        #pragma unroll
        for (int nt = 0; nt < 4; ++nt) {
            const int a = (nt * 16 + l15) * 72 + ks * 32 + quad * 8;
            vfh[nt] = *reinterpret_cast<const bf16x8*>(&VsH[a]);
            vfl[nt] = *reinterpret_cast<const bf16x8*>(&VsL[a]);
        }
        #pragma unroll
        for (int nt = 0; nt < 4; ++nt) {
            oacc[nt] = __builtin_amdgcn_mfma_f32_16x16x32_bf16(pa, vfh[nt], oacc[nt], 0, 0, 0);
            oacc[nt] = __builtin_amdgcn_mfma_f32_16x16x32_bf16(pa, vfl[nt], oacc[nt], 0, 0, 0);
        }
    }
}

// ---------------------------------------------------------------------------
// MFMA flash attention v4: TWO q-windows per block (t0 and t0+16), sharing
// every staged K/V tile -> staging traffic halves, MFMA/barrier doubles.
// Grid B*G*(T/32)=512 blocks -> fully co-resident (3 blocks/CU), heavy+light
// pairing per CU. blockIdx&7 -> (b,g) for XCD/L2 locality.
// ---------------------------------------------------------------------------
__global__ __launch_bounds__(256) void attn_mfma_kernel(
    const u16* __restrict__ Qh, const u16* __restrict__ Ql,
    const u16* __restrict__ Kh, const u16* __restrict__ Kl,
    const u16* __restrict__ Vth, const u16* __restrict__ Vtl,
    u16* __restrict__ AOh, u16* __restrict__ AOl)
{
    __shared__ u16 KsH[64 * 72];
    __shared__ u16 KsL[64 * 72];
    __shared__ u16 VsH[64 * 72];
    __shared__ u16 VsL[64 * 72];
    __shared__ u16 Ps[4][16 * 72];

    const int tid = threadIdx.x;
    const int wave = tid >> 6, lane = tid & 63;
    const int l15 = lane & 15, quad = lane >> 4;

    const int bg = blockIdx.x & 7;
    const int b = bg >> 2, g = bg & 3;
    const int wp = 63 - (blockIdx.x >> 3);     // heavy-first window pair
    const int t0a = wp * 32;
    const int t0b = t0a + 16;
    const int h = g * 4 + wave;

    bf16x8 qha[2], qla[2], qhb[2], qlb[2];
    {
        const size_t ra = (size_t)(b * Tseq + t0a + l15) * 1024 + h * 64;
        const size_t rb = (size_t)(b * Tseq + t0b + l15) * 1024 + h * 64;
        #pragma unroll
        for (int ks = 0; ks < 2; ++ks) {
            qha[ks] = *reinterpret_cast<const bf16x8*>(&Qh[ra + ks * 32 + quad * 8]);
            qla[ks] = *reinterpret_cast<const bf16x8*>(&Ql[ra + ks * 32 + quad * 8]);
            qhb[ks] = *reinterpret_cast<const bf16x8*>(&Qh[rb + ks * 32 + quad * 8]);
            qlb[ks] = *reinterpret_cast<const bf16x8*>(&Ql[rb + ks * 32 + quad * 8]);
        }
    }

    const int srow = tid >> 2;
    const int scol = (tid & 3) * 16;
    const size_t kgb = (size_t)(b * Tseq) * 256 + g * 64 + scol;
    const size_t vgb = (size_t)(bg * 64 + srow) * Tseq + scol;

    const int nit = t0b / 64 + 1;

    uint4 ck0, ck1, cl0, cl1, cv0, cv1, cw0, cw1;
    {
        const size_t ka = kgb + (size_t)srow * 256;
        ck0 = *reinterpret_cast<const uint4*>(&Kh[ka]);
        ck1 = *reinterpret_cast<const uint4*>(&Kh[ka + 8]);
        cl0 = *reinterpret_cast<const uint4*>(&Kl[ka]);
        cl1 = *reinterpret_cast<const uint4*>(&Kl[ka + 8]);
        cv0 = *reinterpret_cast<const uint4*>(&Vth[vgb]);
        cv1 = *reinterpret_cast<const uint4*>(&Vth[vgb + 8]);
        cw0 = *reinterpret_cast<const uint4*>(&Vtl[vgb]);
        cw1 = *reinterpret_cast<const uint4*>(&Vtl[vgb + 8]);
    }

    f32x4 oa[4], ob[4];
    #pragma unroll
    for (int nt = 0; nt < 4; ++nt) {
        oa[nt] = (f32x4){0.f, 0.f, 0.f, 0.f};
        ob[nt] = (f32x4){0.f, 0.f, 0.f, 0.f};
    }
    float ma[4], la[4], mb[4], lb[4];
    #pragma unroll
    for (int r = 0; r < 4; ++r) {
        ma[r] = -1e30f; la[r] = 0.0f;
        mb[r] = -1e30f; lb[r] = 0.0f;
    }

    u16* psw = &Ps[wave][0];
    const int lbo = srow * 72 + scol;

    for (int it = 0; it < nit; ++it) {
        const int s0 = it * 64;

        __syncthreads();
        *reinterpret_cast<uint4*>(&KsH[lbo])     = ck0;
        *reinterpret_cast<uint4*>(&KsH[lbo + 8]) = ck1;
        *reinterpret_cast<uint4*>(&KsL[lbo])     = cl0;
        *reinterpret_cast<uint4*>(&KsL[lbo + 8]) = cl1;
        *reinterpret_cast<uint4*>(&VsH[lbo])     = cv0;
        *reinterpret_cast<uint4*>(&VsH[lbo + 8]) = cv1;
        *reinterpret_cast<uint4*>(&VsL[lbo])     = cw0;
        *reinterpret_cast<uint4*>(&VsL[lbo + 8]) = cw1;
        if (it + 1 < nit) {
            const size_t ka = kgb + (size_t)(s0 + 64 + srow) * 256;
            ck0 = *reinterpret_cast<const uint4*>(&Kh[ka]);
            ck1 = *reinterpret_cast<const uint4*>(&Kh[ka + 8]);
            cl0 = *reinterpret_cast<const uint4*>(&Kl[ka]);
            cl1 = *reinterpret_cast<const uint4*>(&Kl[ka + 8]);
            const size_t va = vgb + s0 + 64;
            cv0 = *reinterpret_cast<const uint4*>(&Vth[va]);
            cv1 = *reinterpret_cast<const uint4*>(&Vth[va + 8]);
            cw0 = *reinterpret_cast<const uint4*>(&Vtl[va]);
            cw1 = *reinterpret_cast<const uint4*>(&Vtl[va + 8]);
        }
        __syncthreads();

        if (s0 <= t0a + 15)   // block-uniform branch
            attn_strip_step(qha, qla, KsH, KsL, VsH, VsL, psw,
                            s0, t0a, l15, quad, oa, ma, la);
        attn_strip_step(qhb, qlb, KsH, KsL, VsH, VsL, psw,
                        s0, t0b, l15, quad, ob, mb, lb);
    }

    #pragma unroll
    for (int r = 0; r < 4; ++r) {
        const float inva = 1.0f / la[r];
        const float invb = 1.0f / lb[r];
        const size_t rowa = (size_t)(b * Tseq + t0a + quad * 4 + r) * 1024 + h * 64;
        const size_t rowb = (size_t)(b * Tseq + t0b + quad * 4 + r) * 1024 + h * 64;
        #pragma unroll
        for (int nt = 0; nt < 4; ++nt) {
            const float o1 = oa[nt][r] * inva;
            const float o2 = ob[nt][r] * invb;
            const u16 h1 = f2bf(o1);
            const u16 h2 = f2bf(o2);
            AOh[rowa + nt * 16 + l15] = h1;
            AOl[rowa + nt * 16 + l15] = f2bf(o1 - bf2f(h1));
            AOh[rowb + nt * 16 + l15] = h2;
            AOl[rowb + nt * 16 + l15] = f2bf(o2 - bf2f(h2));
        }
    }
}

// ---------------------------------------------------------------------------
// Host launcher
// ---------------------------------------------------------------------------
extern "C" void kernel_launch(void* const* d_in, const int* in_sizes, int n_in,
                              void* d_out, int out_size, void* d_ws,
                              size_t ws_size, hipStream_t stream)
{
    const float* hidden = (const float*)d_in[0];
    const float* sinp   = (const float*)d_in[1];
    const float* cosp   = (const float*)d_in[2];
    // d_in[3] = mask — causal, handled analytically
    const float* ln1    = (const float*)d_in[4];
    const float* ln2    = (const float*)d_in[5];
    const float* qn     = (const float*)d_in[6];
    const float* kn     = (const float*)d_in[7];
    const float* q_w    = (const float*)d_in[8];
    const float* k_w    = (const float*)d_in[9];
    const float* v_w    = (const float*)d_in[10];
    const float* o_w    = (const float*)d_in[11];
    const float* gate_w = (const float*)d_in[12];
    const float* up_w   = (const float*)d_in[13];
    const float* down_w = (const float*)d_in[14];
    float* out = (float*)d_out;

    // ---- workspace layout (116.4 MB; capacity >= 120.6 MB proven r8) ----
    char* base = (char*)d_ws;
    u16*   OTh  = (u16*)(base);                //  2 MB
    u16*   OTl  = (u16*)(base + 2097152);      //  2 MB
    u16*   GTh  = (u16*)(base + 4194304);      //  8 MB
    u16*   UTh  = (u16*)(base + 12582912);     //  8 MB
    u16*   DTh  = (u16*)(base + 20971520);     //  8 MB
    u16*   QKVT = (u16*)(base + 29360128);     //  3 MB
    u16*   Xh   = (u16*)(base + 32505856);     //  8 MB
    u16*   Qbh  = (u16*)(base + 40894464);     //  8 MB
    u16*   Qbl  = (u16*)(base + 49283072);     //  8 MB
    u16*   Kbh  = (u16*)(base + 57671680);     //  2 MB
    u16*   Kbl  = (u16*)(base + 59768832);     //  2 MB
    u16*   Vth  = (u16*)(base + 61865984);     //  2 MB
    u16*   Vtl  = (u16*)(base + 63963136);     //  2 MB
    u16*   AOh  = (u16*)(base + 66060288);     //  8 MB
    u16*   AOl  = (u16*)(base + 74448896);     //  8 MB
    u16*   FFh  = (u16*)(base + 82837504);     // 32 MB (end 116,391,936)

    // aliases (lifetime-checked):
    float* H2 = (float*)Qbh;   // 16 MB over Qbh+Qbl (Q dead post-attn)
    u16*   Yh = Kbh;           //  8 MB over Kbh..Vtl (K/V dead post-attn)
    u16*   Yl = AOh;           //  8 MB over AOh (AO dead post-o-proj)

    // 0. all weight prep, one launch
    wprep_all_kernel<<<14848, 256, 0, stream>>>(
        q_w, k_w, v_w, o_w, gate_w, up_w, down_w,
        QKVT, OTh, OTl, GTh, UTh, DTh);

    // 1. x = rmsnorm(hidden, ln1) -> bf16
    rmsnorm_split_kernel<0><<<Mrows, 256, 0, stream>>>(hidden, ln1, Xh, nullptr);

    // 2. fused qkv projection + qknorm + rope + split + V-transpose
    qkv_fused_kernel<<<dim3(12, 32), 256, 0, stream>>>(
        Xh, QKVT, qn, kn, sinp, cosp, Qbh, Qbl, Kbh, Kbl, Vth, Vtl);

    // 3. MFMA flash attention v4 (2 windows/block) -> AO bf16 hi/lo
    attn_mfma_kernel<<<Bsz * Gg * (Tseq / 32), 256, 0, stream>>>(
        Qbh, Qbl, Kbh, Kbl, Vth, Vtl, AOh, AOl);

    // 4. hidden2 = hidden + attn @ o_w  (split x split)
    mfma_gemm_kernel<1, 1, 1><<<dim3(8, 32), 256, 0, stream>>>(
        AOh, AOl, OTh, OTl, hidden, H2, Mrows, Dmod, 1024);

    // 5. y = rmsnorm(hidden2, ln2) -> bf16 hi/lo
    rmsnorm_split_kernel<1><<<Mrows, 256, 0, stream>>>(H2, ln2, Yh, Yl);

    // 6. ff = silu(y@gate_w) * (y@up_w) -> FF bf16  (128x64 tiles)
    mfma_gateup_kernel<<<dim3(Ff / 64, Mrows / 128), 256, 0, stream>>>(
        Yh, Yl, GTh, UTh, FFh, Mrows, Ff, 1024);

    // 7. out = hidden2 + ff @ down_w
    mfma_gemm_kernel<0, 0, 1><<<dim3(8, 32), 256, 0, stream>>>(
        FFh, nullptr, DTh, nullptr, H2, out, Mrows, Dmod, 4096);
}

// Round 10
// 532.358 us; speedup vs baseline: 1.0712x; 1.0712x over previous
//
#include <hip/hip_runtime.h>
#include <hip/hip_bf16.h>

// Problem constants: B=2, T=2048, D=1024, H=16, G=4, K=64, F=4096
#define EPSF 1e-6f
constexpr int Bsz  = 2;
constexpr int Tseq = 2048;
constexpr int Dmod = 1024;
constexpr int Hh   = 16;
constexpr int Gg   = 4;
constexpr int Ff   = 4096;
constexpr int Mrows = Bsz * Tseq;          // 4096 tokens

typedef __attribute__((ext_vector_type(8))) short bf16x8;   // 8 bf16 (4 VGPRs)
typedef __attribute__((ext_vector_type(4))) float f32x4;
typedef unsigned short u16;

// RNE fp32 -> bf16 (bit pattern as u16)
__device__ inline u16 f2bf(float x) {
    union { float f; unsigned u; } v; v.f = x;
    unsigned r = v.u + 0x7fff + ((v.u >> 16) & 1);
    return (u16)(r >> 16);
}
__device__ inline float bf2f(u16 h) {
    union { unsigned u; float f; } v; v.u = ((unsigned)h) << 16; return v.f;
}

// Async global->LDS DMA, 16 B per lane (wave-uniform base + lane*16).
__device__ __forceinline__ void async_copy16(const u16* g, u16* l) {
    __builtin_amdgcn_global_load_lds(
        (const __attribute__((address_space(1))) void*)g,
        (__attribute__((address_space(3))) void*)l, 16, 0, 0);
}

// Bank-swizzle: LDS tiles [row][32] bf16 (64 B rows). Logical k-chunk q of row
// R stored at chunk q ^ ((R>>1)&3); staging fetches global chunk
// (lane&3)^((row>>1)&3) into linear dest lane*16; reads XOR the same term.
// -> 2-way (free) instead of 8-way conflicts (verified r7: conflicts = 0).

// ---------------------------------------------------------------------------
// ALL weight prep in ONE launch (kept from r9 — sound). 14848 blocks.
// ---------------------------------------------------------------------------
__global__ __launch_bounds__(256) void wprep_all_kernel(
    const float* __restrict__ q_w, const float* __restrict__ k_w,
    const float* __restrict__ v_w, const float* __restrict__ o_w,
    const float* __restrict__ gate_w, const float* __restrict__ up_w,
    const float* __restrict__ down_w,
    u16* __restrict__ QKVT, u16* __restrict__ OTh, u16* __restrict__ OTl,
    u16* __restrict__ GTh, u16* __restrict__ UTh, u16* __restrict__ DTh)
{
    const int bx = blockIdx.x;
    const float* W; u16* Th; u16* Tl = nullptr;
    int N, Kd, ntile, ktile, drow;
    if (bx < 1024) {
        W = q_w; N = 1024; Kd = 1024; ntile = bx & 31; ktile = bx >> 5;
        Th = QKVT; drow = ntile * 32;
    } else if (bx < 1280) {
        const int i = bx - 1024;
        W = k_w; N = 256; Kd = 1024; ntile = i & 7; ktile = i >> 3;
        Th = QKVT; drow = 1024 + ntile * 32;
    } else if (bx < 1536) {
        const int i = bx - 1280;
        W = v_w; N = 256; Kd = 1024; ntile = i & 7; ktile = i >> 3;
        Th = QKVT; drow = 1280 + ntile * 32;
    } else if (bx < 2560) {
        const int i = bx - 1536;
        W = o_w; N = 1024; Kd = 1024; ntile = i & 31; ktile = i >> 5;
        Th = OTh; Tl = OTl; drow = ntile * 32;
    } else if (bx < 6656) {
        const int i = bx - 2560;
        W = gate_w; N = 4096; Kd = 1024; ntile = i & 127; ktile = i >> 7;
        Th = GTh; drow = ntile * 32;
    } else if (bx < 10752) {
        const int i = bx - 6656;
        W = up_w; N = 4096; Kd = 1024; ntile = i & 127; ktile = i >> 7;
        Th = UTh; drow = ntile * 32;
    } else {
        const int i = bx - 10752;
        W = down_w; N = 1024; Kd = 4096; ntile = i & 31; ktile = i >> 5;
        Th = DTh; drow = ntile * 32;
    }
    const int n0 = ntile * 32, k0 = ktile * 32;

    __shared__ float tile[32][33];
    const int r = threadIdx.x >> 3, c4 = (threadIdx.x & 7) * 4;
    const float4 v = *reinterpret_cast<const float4*>(&W[(size_t)(k0 + r) * N + n0 + c4]);
    tile[r][c4 + 0] = v.x; tile[r][c4 + 1] = v.y;
    tile[r][c4 + 2] = v.z; tile[r][c4 + 3] = v.w;
    __syncthreads();
    const int nl = threadIdx.x >> 3, kq = (threadIdx.x & 7) * 4;
    float x0 = tile[kq + 0][nl], x1 = tile[kq + 1][nl];
    float x2 = tile[kq + 2][nl], x3 = tile[kq + 3][nl];
    ushort4 h;
    h.x = f2bf(x0); h.y = f2bf(x1); h.z = f2bf(x2); h.w = f2bf(x3);
    *reinterpret_cast<ushort4*>(&Th[(size_t)(drow + nl) * Kd + k0 + kq]) = h;
    if (Tl) {
        ushort4 l;
        l.x = f2bf(x0 - bf2f(h.x)); l.y = f2bf(x1 - bf2f(h.y));
        l.z = f2bf(x2 - bf2f(h.z)); l.w = f2bf(x3 - bf2f(h.w));
        *reinterpret_cast<ushort4*>(&Tl[(size_t)(drow + nl) * Kd + k0 + kq]) = l;
    }
}

// ---------------------------------------------------------------------------
// RMSNorm over D=1024 -> bf16 hi (+ optional lo). One block per token.
// ---------------------------------------------------------------------------
template <int LO>
__global__ __launch_bounds__(256) void rmsnorm_split_kernel(
    const float* __restrict__ x, const float* __restrict__ scale,
    u16* __restrict__ oh, u16* __restrict__ ol)
{
    const int row = blockIdx.x;
    const int tid = threadIdx.x;
    const float4 v = reinterpret_cast<const float4*>(x + (size_t)row * Dmod)[tid];
    float ss = v.x * v.x + v.y * v.y + v.z * v.z + v.w * v.w;
    #pragma unroll
    for (int off = 32; off; off >>= 1) ss += __shfl_xor(ss, off, 64);
    __shared__ float part[4];
    if ((tid & 63) == 0) part[tid >> 6] = ss;
    __syncthreads();
    const float tot = part[0] + part[1] + part[2] + part[3];
    const float rstd = rsqrtf(tot * (1.0f / Dmod) + EPSF);
    const float4 sc = reinterpret_cast<const float4*>(scale)[tid];
    float o0 = v.x * rstd * sc.x, o1 = v.y * rstd * sc.y;
    float o2 = v.z * rstd * sc.z, o3 = v.w * rstd * sc.w;
    ushort4 h;
    h.x = f2bf(o0); h.y = f2bf(o1); h.z = f2bf(o2); h.w = f2bf(o3);
    *reinterpret_cast<ushort4*>(&oh[(size_t)row * Dmod + tid * 4]) = h;
    if (LO) {
        ushort4 l;
        l.x = f2bf(o0 - bf2f(h.x)); l.y = f2bf(o1 - bf2f(h.y));
        l.z = f2bf(o2 - bf2f(h.z)); l.w = f2bf(o3 - bf2f(h.w));
        *reinterpret_cast<ushort4*>(&ol[(size_t)row * Dmod + tid * 4]) = l;
    }
}

// ---------------------------------------------------------------------------
// Split-bf16 MFMA GEMM, async DMA + swizzle (unchanged from r7).
// ---------------------------------------------------------------------------
template <int ASPLIT, int BSPLIT, int RES>
__global__ __launch_bounds__(256, 2) void mfma_gemm_kernel(
    const u16* __restrict__ Ah, const u16* __restrict__ Al,
    const u16* __restrict__ Bh, const u16* __restrict__ Bl,
    const float* __restrict__ res, float* __restrict__ C,
    int M, int N, int Kd)
{
    __shared__ u16 As_h[128 * 32];
    __shared__ u16 As_l[128 * 32];
    __shared__ u16 Bs_h[128 * 32];
    __shared__ u16 Bs_l[128 * 32];

    const int tid = threadIdx.x;
    const int lane = tid & 63, wave = tid >> 6;
    const int wm = (wave >> 1) * 64, wn = (wave & 1) * 64;
    const int m0 = blockIdx.y * 128, n0 = blockIdx.x * 128;
    const int fm = lane & 15, quad = lane >> 4;
    const int fsw = (fm >> 1) & 3;
    const int fcol = ((quad ^ fsw) * 8);

    f32x4 acc[4][4];
    #pragma unroll
    for (int i = 0; i < 4; ++i)
        #pragma unroll
        for (int j = 0; j < 4; ++j) acc[i][j] = (f32x4){0.f, 0.f, 0.f, 0.f};

    const int lrow = lane >> 2;
    const int lchunk = lane & 3;
    const int schunk = lchunk ^ ((lrow >> 1) & 3);

    for (int k0 = 0; k0 < Kd; k0 += 32) {
        __syncthreads();
        #pragma unroll
        for (int p = 0; p < 2; ++p) {
            const int row = wave * 32 + p * 16 + lrow;
            const size_t ga = (size_t)(m0 + row) * Kd + k0 + schunk * 8;
            const size_t gb = (size_t)(n0 + row) * Kd + k0 + schunk * 8;
            const int ls = row * 32 + lchunk * 8;
            async_copy16(&Ah[ga], &As_h[ls]);
            if (ASPLIT) async_copy16(&Al[ga], &As_l[ls]);
            async_copy16(&Bh[gb], &Bs_h[ls]);
            if (BSPLIT) async_copy16(&Bl[gb], &Bs_l[ls]);
        }
        __syncthreads();

        bf16x8 ah[4], al[4], bh[4], bl[4];
        #pragma unroll
        for (int t = 0; t < 4; ++t) {
            const int ra = (wm + t * 16 + fm) * 32 + fcol;
            const int rb = (wn + t * 16 + fm) * 32 + fcol;
            ah[t] = *reinterpret_cast<const bf16x8*>(&As_h[ra]);
            bh[t] = *reinterpret_cast<const bf16x8*>(&Bs_h[rb]);
            if (ASPLIT) al[t] = *reinterpret_cast<const bf16x8*>(&As_l[ra]);
            if (BSPLIT) bl[t] = *reinterpret_cast<const bf16x8*>(&Bs_l[rb]);
        }
        #pragma unroll
        for (int mt = 0; mt < 4; ++mt)
            #pragma unroll
            for (int nt = 0; nt < 4; ++nt) {
                acc[mt][nt] = __builtin_amdgcn_mfma_f32_16x16x32_bf16(
                    ah[mt], bh[nt], acc[mt][nt], 0, 0, 0);
                if (BSPLIT)
                    acc[mt][nt] = __builtin_amdgcn_mfma_f32_16x16x32_bf16(
                        ah[mt], bl[nt], acc[mt][nt], 0, 0, 0);
                if (ASPLIT)
                    acc[mt][nt] = __builtin_amdgcn_mfma_f32_16x16x32_bf16(
                        al[mt], bh[nt], acc[mt][nt], 0, 0, 0);
            }
    }

    const int cr = (lane >> 4) * 4, cn = lane & 15;
    #pragma unroll
    for (int mt = 0; mt < 4; ++mt)
        #pragma unroll
        for (int nt = 0; nt < 4; ++nt)
            #pragma unroll
            for (int r = 0; r < 4; ++r) {
                const int gm = m0 + wm + mt * 16 + cr + r;
                const int gn = n0 + wn + nt * 16 + cn;
                float v = acc[mt][nt][r];
                if (RES) v += res[(size_t)gm * N + gn];
                C[(size_t)gm * N + gn] = v;
            }
}

// ---------------------------------------------------------------------------
// Fused QKV GEMM + qk-norm + RoPE + bf16 split epilogue; V stored TRANSPOSED
// directly (kept from r9 — sound).
// ---------------------------------------------------------------------------
__global__ __launch_bounds__(256, 2) void qkv_fused_kernel(
    const u16* __restrict__ Ah, const u16* __restrict__ Bh,
    const float* __restrict__ qn, const float* __restrict__ kn,
    const float* __restrict__ sinp, const float* __restrict__ cosp,
    u16* __restrict__ Qbh, u16* __restrict__ Qbl,
    u16* __restrict__ Kbh, u16* __restrict__ Kbl,
    u16* __restrict__ Vth, u16* __restrict__ Vtl)
{
    __shared__ u16 As_h[128 * 32];
    __shared__ u16 Bs_h[128 * 32];

    const int Kd = 1024;
    const int tid = threadIdx.x;
    const int lane = tid & 63, wave = tid >> 6;
    const int wm = (wave >> 1) * 64, wn = (wave & 1) * 64;
    const int m0 = blockIdx.y * 128, n0 = blockIdx.x * 128;
    const int fm = lane & 15, quad = lane >> 4;
    const int fsw = (fm >> 1) & 3;
    const int fcol = ((quad ^ fsw) * 8);

    f32x4 acc[4][4];
    #pragma unroll
    for (int i = 0; i < 4; ++i)
        #pragma unroll
        for (int j = 0; j < 4; ++j) acc[i][j] = (f32x4){0.f, 0.f, 0.f, 0.f};

    const int lrow = lane >> 2;
    const int lchunk = lane & 3;
    const int schunk = lchunk ^ ((lrow >> 1) & 3);

    for (int k0 = 0; k0 < Kd; k0 += 32) {
        __syncthreads();
        #pragma unroll
        for (int p = 0; p < 2; ++p) {
            const int row = wave * 32 + p * 16 + lrow;
            const size_t ga = (size_t)(m0 + row) * Kd + k0 + schunk * 8;
            const size_t gb = (size_t)(n0 + row) * Kd + k0 + schunk * 8;
            const int ls = row * 32 + lchunk * 8;
            async_copy16(&Ah[ga], &As_h[ls]);
            async_copy16(&Bh[gb], &Bs_h[ls]);
        }
        __syncthreads();

        bf16x8 ah[4], bh[4];
        #pragma unroll
        for (int t = 0; t < 4; ++t) {
            ah[t] = *reinterpret_cast<const bf16x8*>(&As_h[(wm + t * 16 + fm) * 32 + fcol]);
            bh[t] = *reinterpret_cast<const bf16x8*>(&Bs_h[(wn + t * 16 + fm) * 32 + fcol]);
        }
        #pragma unroll
        for (int mt = 0; mt < 4; ++mt)
            #pragma unroll
            for (int nt = 0; nt < 4; ++nt)
                acc[mt][nt] = __builtin_amdgcn_mfma_f32_16x16x32_bf16(
                    ah[mt], bh[nt], acc[mt][nt], 0, 0, 0);
    }

    const int gn0 = n0 + wn;          // wave col base, 64-aligned
    const int l15 = lane & 15;

    if (gn0 < 1280) {
        // ---- Q or K: per-head RMSNorm + RoPE + split ----
        const bool isQ = (gn0 < 1024);
        const float* nsc = isQ ? qn : kn;
        const float osc = isQ ? 0.125f : 1.0f;
        u16* __restrict__ oh = isQ ? Qbh : Kbh;
        u16* __restrict__ ol = isQ ? Qbl : Kbl;
        const int rowstride = isQ ? 1024 : 256;
        const int colbase = isQ ? gn0 : gn0 - 1024;
        float sc[4];
        #pragma unroll
        for (int nt = 0; nt < 4; ++nt) sc[nt] = nsc[nt * 16 + l15];

        #pragma unroll
        for (int mt = 0; mt < 4; ++mt)
            #pragma unroll
            for (int r = 0; r < 4; ++r) {
                const int bt = m0 + wm + mt * 16 + quad * 4 + r;
                float v[4];
                #pragma unroll
                for (int nt = 0; nt < 4; ++nt) v[nt] = acc[mt][nt][r];
                float ss = v[0] * v[0] + v[1] * v[1] + v[2] * v[2] + v[3] * v[3];
                #pragma unroll
                for (int off = 1; off < 16; off <<= 1)
                    ss += __shfl_xor(ss, off, 16);
                const float rstd = rsqrtf(ss * (1.0f / 64.0f) + EPSF);
                float nv[4];
                #pragma unroll
                for (int nt = 0; nt < 4; ++nt) nv[nt] = v[nt] * rstd * sc[nt];
                const float s0 = sinp[bt * 32 + l15];
                const float c0 = cosp[bt * 32 + l15];
                const float s1 = sinp[bt * 32 + 16 + l15];
                const float c1 = cosp[bt * 32 + 16 + l15];
                float o[4];
                o[0] = (nv[0] * c0 - nv[2] * s0) * osc;
                o[1] = (nv[1] * c1 - nv[3] * s1) * osc;
                o[2] = (nv[2] * c0 + nv[0] * s0) * osc;
                o[3] = (nv[3] * c1 + nv[1] * s1) * osc;
                #pragma unroll
                for (int nt = 0; nt < 4; ++nt) {
                    const size_t off = (size_t)bt * rowstride + colbase + nt * 16 + l15;
                    const u16 hi = f2bf(o[nt]);
                    oh[off] = hi;
                    ol[off] = f2bf(o[nt] - bf2f(hi));
                }
            }
    } else {
        // ---- V: bf16 split, stored transposed: Vt[(b*4+g)*64+d][t] ----
        const int g = (gn0 - 1280) >> 6;
        const int b = (m0 + wm) >> 11;
        const int tb = ((m0 + wm) & 2047) + quad * 4;
        #pragma unroll
        for (int mt = 0; mt < 4; ++mt)
            #pragma unroll
            for (int nt = 0; nt < 4; ++nt) {
                const float v0 = acc[mt][nt][0], v1 = acc[mt][nt][1];
                const float v2 = acc[mt][nt][2], v3 = acc[mt][nt][3];
                ushort4 hv, lv;
                hv.x = f2bf(v0); hv.y = f2bf(v1); hv.z = f2bf(v2); hv.w = f2bf(v3);
                lv.x = f2bf(v0 - bf2f(hv.x)); lv.y = f2bf(v1 - bf2f(hv.y));
                lv.z = f2bf(v2 - bf2f(hv.z)); lv.w = f2bf(v3 - bf2f(hv.w));
                const size_t off =
                    ((size_t)((b * 4 + g) * 64 + nt * 16 + l15)) * Tseq + tb + mt * 16;
                *reinterpret_cast<ushort4*>(&Vth[off]) = hv;
                *reinterpret_cast<ushort4*>(&Vtl[off]) = lv;
            }
    }
}

// ---------------------------------------------------------------------------
// Fused gate/up MFMA GEMM + silu epilogue (unchanged from r7).
// ---------------------------------------------------------------------------
__global__ __launch_bounds__(256, 2) void mfma_gateup_kernel(
    const u16* __restrict__ Ah, const u16* __restrict__ Al,
    const u16* __restrict__ Bg, const u16* __restrict__ Bu,
    u16* __restrict__ FF, int M, int N, int Kd)
{
    __shared__ u16 As_h[128 * 32];
    __shared__ u16 As_l[128 * 32];
    __shared__ u16 Gs[64 * 32];
    __shared__ u16 Us[64 * 32];

    const int tid = threadIdx.x;
    const int lane = tid & 63, wave = tid >> 6;
    const int wm = (wave >> 1) * 64, wn = (wave & 1) * 32;
    const int m0 = blockIdx.y * 128, n0 = blockIdx.x * 64;
    const int fm = lane & 15, quad = lane >> 4;
    const int fsw = (fm >> 1) & 3;
    const int fcol = ((quad ^ fsw) * 8);

    f32x4 accg[4][2], accu[4][2];
    #pragma unroll
    for (int i = 0; i < 4; ++i)
        #pragma unroll
        for (int j = 0; j < 2; ++j) {
            accg[i][j] = (f32x4){0.f, 0.f, 0.f, 0.f};
            accu[i][j] = (f32x4){0.f, 0.f, 0.f, 0.f};
        }

    const int lrow = lane >> 2;
    const int lchunk = lane & 3;
    const int schunk = lchunk ^ ((lrow >> 1) & 3);

    for (int k0 = 0; k0 < Kd; k0 += 32) {
        __syncthreads();
        #pragma unroll
        for (int p = 0; p < 2; ++p) {
            const int row = p * 64 + wave * 16 + lrow;
            const size_t ga = (size_t)(m0 + row) * Kd + k0 + schunk * 8;
            const int ls = row * 32 + lchunk * 8;
            async_copy16(&Ah[ga], &As_h[ls]);
            async_copy16(&Al[ga], &As_l[ls]);
        }
        {
            const int row = wave * 16 + lrow;
            const size_t gb = (size_t)(n0 + row) * Kd + k0 + schunk * 8;
            const int ls = row * 32 + lchunk * 8;
            async_copy16(&Bg[gb], &Gs[ls]);
            async_copy16(&Bu[gb], &Us[ls]);
        }
        __syncthreads();

        bf16x8 a_h[4], a_l[4], g_f[2], u_f[2];
        #pragma unroll
        for (int t = 0; t < 4; ++t) {
            const int ra = (wm + t * 16 + fm) * 32 + fcol;
            a_h[t] = *reinterpret_cast<const bf16x8*>(&As_h[ra]);
            a_l[t] = *reinterpret_cast<const bf16x8*>(&As_l[ra]);
        }
        #pragma unroll
        for (int j = 0; j < 2; ++j) {
            const int rb = (wn + j * 16 + fm) * 32 + fcol;
            g_f[j] = *reinterpret_cast<const bf16x8*>(&Gs[rb]);
            u_f[j] = *reinterpret_cast<const bf16x8*>(&Us[rb]);
        }
        #pragma unroll
        for (int mt = 0; mt < 4; ++mt)
            #pragma unroll
            for (int nt = 0; nt < 2; ++nt) {
                accg[mt][nt] = __builtin_amdgcn_mfma_f32_16x16x32_bf16(
                    a_h[mt], g_f[nt], accg[mt][nt], 0, 0, 0);
                accg[mt][nt] = __builtin_amdgcn_mfma_f32_16x16x32_bf16(
                    a_l[mt], g_f[nt], accg[mt][nt], 0, 0, 0);
                accu[mt][nt] = __builtin_amdgcn_mfma_f32_16x16x32_bf16(
                    a_h[mt], u_f[nt], accu[mt][nt], 0, 0, 0);
                accu[mt][nt] = __builtin_amdgcn_mfma_f32_16x16x32_bf16(
                    a_l[mt], u_f[nt], accu[mt][nt], 0, 0, 0);
            }
    }

    const int cr = (lane >> 4) * 4, cn = lane & 15;
    #pragma unroll
    for (int mt = 0; mt < 4; ++mt)
        #pragma unroll
        for (int nt = 0; nt < 2; ++nt)
            #pragma unroll
            for (int r = 0; r < 4; ++r) {
                const int gm = m0 + wm + mt * 16 + cr + r;
                const int gn = n0 + wn + nt * 16 + cn;
                const float g = accg[mt][nt][r];
                const float ff = (g / (1.0f + __expf(-g))) * accu[mt][nt][r];
                FF[(size_t)gm * N + gn] = f2bf(ff);
            }
}

// ---------------------------------------------------------------------------
// MFMA flash attention v3 (EXACT r8 revert — one 16-row window per block;
// v4's window-pairing doubled the heaviest block's critical path and
// regressed; see r9 post-mortem).
// ---------------------------------------------------------------------------
__global__ __launch_bounds__(256) void attn_mfma_kernel(
    const u16* __restrict__ Qh, const u16* __restrict__ Ql,
    const u16* __restrict__ Kh, const u16* __restrict__ Kl,
    const u16* __restrict__ Vth, const u16* __restrict__ Vtl,
    u16* __restrict__ AOh, u16* __restrict__ AOl)
{
    __shared__ u16 KsH[64 * 72];
    __shared__ u16 KsL[64 * 72];
    __shared__ u16 VsH[64 * 72];
    __shared__ u16 VsL[64 * 72];
    __shared__ u16 Ps[4][16 * 72];

    const int tid = threadIdx.x;
    const int wave = tid >> 6, lane = tid & 63;
    const int l15 = lane & 15, quad = lane >> 4;

    const int bg = blockIdx.x & 7;
    const int b = bg >> 2, g = bg & 3;
    const int win = 127 - (blockIdx.x >> 3);
    const int t0 = win * 16;
    const int h = g * 4 + wave;

    bf16x8 qh[2], ql[2];
    {
        const size_t qrow = (size_t)(b * Tseq + t0 + l15) * 1024 + h * 64;
        #pragma unroll
        for (int ks = 0; ks < 2; ++ks) {
            qh[ks] = *reinterpret_cast<const bf16x8*>(&Qh[qrow + ks * 32 + quad * 8]);
            ql[ks] = *reinterpret_cast<const bf16x8*>(&Ql[qrow + ks * 32 + quad * 8]);
        }
    }

    const int srow = tid >> 2;
    const int scol = (tid & 3) * 16;
    const size_t kgb = (size_t)(b * Tseq) * 256 + g * 64 + scol;
    const size_t vgb = (size_t)(bg * 64 + srow) * Tseq + scol;

    const int nit = t0 / 64 + 1;

    uint4 ck0, ck1, cl0, cl1, cv0, cv1, cw0, cw1;
    {
        const size_t ka = kgb + (size_t)srow * 256;
        ck0 = *reinterpret_cast<const uint4*>(&Kh[ka]);
        ck1 = *reinterpret_cast<const uint4*>(&Kh[ka + 8]);
        cl0 = *reinterpret_cast<const uint4*>(&Kl[ka]);
        cl1 = *reinterpret_cast<const uint4*>(&Kl[ka + 8]);
        cv0 = *reinterpret_cast<const uint4*>(&Vth[vgb]);
        cv1 = *reinterpret_cast<const uint4*>(&Vth[vgb + 8]);
        cw0 = *reinterpret_cast<const uint4*>(&Vtl[vgb]);
        cw1 = *reinterpret_cast<const uint4*>(&Vtl[vgb + 8]);
    }

    f32x4 oacc[4];
    #pragma unroll
    for (int nt = 0; nt < 4; ++nt) oacc[nt] = (f32x4){0.f, 0.f, 0.f, 0.f};
    float m_r[4], l_r[4];
    #pragma unroll
    for (int r = 0; r < 4; ++r) { m_r[r] = -1e30f; l_r[r] = 0.0f; }

    u16* psw = &Ps[wave][0];
    const int lb = srow * 72 + scol;

    for (int it = 0; it < nit; ++it) {
        const int s0 = it * 64;
        const bool diag = (it == nit - 1);

        __syncthreads();
        *reinterpret_cast<uint4*>(&KsH[lb])     = ck0;
        *reinterpret_cast<uint4*>(&KsH[lb + 8]) = ck1;
        *reinterpret_cast<uint4*>(&KsL[lb])     = cl0;
        *reinterpret_cast<uint4*>(&KsL[lb + 8]) = cl1;
        *reinterpret_cast<uint4*>(&VsH[lb])     = cv0;
        *reinterpret_cast<uint4*>(&VsH[lb + 8]) = cv1;
        *reinterpret_cast<uint4*>(&VsL[lb])     = cw0;
        *reinterpret_cast<uint4*>(&VsL[lb + 8]) = cw1;
        if (it + 1 < nit) {
            const size_t ka = kgb + (size_t)(s0 + 64 + srow) * 256;
            ck0 = *reinterpret_cast<const uint4*>(&Kh[ka]);
            ck1 = *reinterpret_cast<const uint4*>(&Kh[ka + 8]);
            cl0 = *reinterpret_cast<const uint4*>(&Kl[ka]);
            cl1 = *reinterpret_cast<const uint4*>(&Kl[ka + 8]);
            const size_t va = vgb + s0 + 64;
            cv0 = *reinterpret_cast<const uint4*>(&Vth[va]);
            cv1 = *reinterpret_cast<const uint4*>(&Vth[va + 8]);
            cw0 = *reinterpret_cast<const uint4*>(&Vtl[va]);
            cw1 = *reinterpret_cast<const uint4*>(&Vtl[va + 8]);
        }
        __syncthreads();

        f32x4 sacc[4];
        #pragma unroll
        for (int nt = 0; nt < 4; ++nt) sacc[nt] = (f32x4){0.f, 0.f, 0.f, 0.f};

        #pragma unroll
        for (int ks = 0; ks < 2; ++ks) {
            bf16x8 kfh[4], kfl[4];
            #pragma unroll
            for (int nt = 0; nt < 4; ++nt) {
                const int a = (nt * 16 + l15) * 72 + ks * 32 + quad * 8;
                kfh[nt] = *reinterpret_cast<const bf16x8*>(&KsH[a]);
                kfl[nt] = *reinterpret_cast<const bf16x8*>(&KsL[a]);
            }
            #pragma unroll
            for (int nt = 0; nt < 4; ++nt) {
                sacc[nt] = __builtin_amdgcn_mfma_f32_16x16x32_bf16(qh[ks], kfh[nt], sacc[nt], 0, 0, 0);
                sacc[nt] = __builtin_amdgcn_mfma_f32_16x16x32_bf16(ql[ks], kfh[nt], sacc[nt], 0, 0, 0);
                sacc[nt] = __builtin_amdgcn_mfma_f32_16x16x32_bf16(qh[ks], kfl[nt], sacc[nt], 0, 0, 0);
            }
        }

        if (diag) {
            #pragma unroll
            for (int nt = 0; nt < 4; ++nt) {
                const int sg = s0 + nt * 16 + l15;
                #pragma unroll
                for (int r = 0; r < 4; ++r)
                    if (sg > t0 + quad * 4 + r) sacc[nt][r] = -1e30f;
            }
        }

        #pragma unroll
        for (int r = 0; r < 4; ++r) {
            float mx = fmaxf(fmaxf(sacc[0][r], sacc[1][r]),
                             fmaxf(sacc[2][r], sacc[3][r]));
            #pragma unroll
            for (int off = 1; off < 16; off <<= 1)
                mx = fmaxf(mx, __shfl_xor(mx, off, 16));
            const float mnew = fmaxf(m_r[r], mx);
            const float alpha = __expf(m_r[r] - mnew);
            m_r[r] = mnew;

            float rs = 0.0f;
            #pragma unroll
            for (int nt = 0; nt < 4; ++nt) {
                const float p = __expf(sacc[nt][r] - mnew);
                sacc[nt][r] = p;
                rs += p;
            }
            #pragma unroll
            for (int off = 1; off < 16; off <<= 1)
                rs += __shfl_xor(rs, off, 16);
            l_r[r] = l_r[r] * alpha + rs;
            #pragma unroll
            for (int nt = 0; nt < 4; ++nt) oacc[nt][r] *= alpha;
            #pragma unroll
            for (int nt = 0; nt < 4; ++nt)
                psw[(quad * 4 + r) * 72 + nt * 16 + l15] = f2bf(sacc[nt][r]);
        }

        #pragma unroll
        for (int ks = 0; ks < 2; ++ks) {
            const bf16x8 pa = *reinterpret_cast<const bf16x8*>(
                &psw[l15 * 72 + ks * 32 + quad * 8]);
            bf16x8 vfh[4], vfl[4];
            #pragma unroll
            for (int nt = 0; nt < 4; ++nt) {
                const int a = (nt * 16 + l15) * 72 + ks * 32 + quad * 8;
                vfh[nt] = *reinterpret_cast<const bf16x8*>(&VsH[a]);
                vfl[nt] = *reinterpret_cast<const bf16x8*>(&VsL[a]);
            }
            #pragma unroll
            for (int nt = 0; nt < 4; ++nt) {
                oacc[nt] = __builtin_amdgcn_mfma_f32_16x16x32_bf16(pa, vfh[nt], oacc[nt], 0, 0, 0);
                oacc[nt] = __builtin_amdgcn_mfma_f32_16x16x32_bf16(pa, vfl[nt], oacc[nt], 0, 0, 0);
            }
        }
    }

    #pragma unroll
    for (int r = 0; r < 4; ++r) {
        const float inv = 1.0f / l_r[r];
        const size_t orow = (size_t)(b * Tseq + t0 + quad * 4 + r) * 1024 + h * 64;
        #pragma unroll
        for (int nt = 0; nt < 4; ++nt) {
            const float o = oacc[nt][r] * inv;
            const u16 hi = f2bf(o);
            AOh[orow + nt * 16 + l15] = hi;
            AOl[orow + nt * 16 + l15] = f2bf(o - bf2f(hi));
        }
    }
}

// ---------------------------------------------------------------------------
// Host launcher
// ---------------------------------------------------------------------------
extern "C" void kernel_launch(void* const* d_in, const int* in_sizes, int n_in,
                              void* d_out, int out_size, void* d_ws,
                              size_t ws_size, hipStream_t stream)
{
    const float* hidden = (const float*)d_in[0];
    const float* sinp   = (const float*)d_in[1];
    const float* cosp   = (const float*)d_in[2];
    // d_in[3] = mask — causal, handled analytically
    const float* ln1    = (const float*)d_in[4];
    const float* ln2    = (const float*)d_in[5];
    const float* qn     = (const float*)d_in[6];
    const float* kn     = (const float*)d_in[7];
    const float* q_w    = (const float*)d_in[8];
    const float* k_w    = (const float*)d_in[9];
    const float* v_w    = (const float*)d_in[10];
    const float* o_w    = (const float*)d_in[11];
    const float* gate_w = (const float*)d_in[12];
    const float* up_w   = (const float*)d_in[13];
    const float* down_w = (const float*)d_in[14];
    float* out = (float*)d_out;

    // ---- workspace layout (116.4 MB; capacity >= 120.6 MB proven r8) ----
    char* base = (char*)d_ws;
    u16*   OTh  = (u16*)(base);                //  2 MB
    u16*   OTl  = (u16*)(base + 2097152);      //  2 MB
    u16*   GTh  = (u16*)(base + 4194304);      //  8 MB
    u16*   UTh  = (u16*)(base + 12582912);     //  8 MB
    u16*   DTh  = (u16*)(base + 20971520);     //  8 MB
    u16*   QKVT = (u16*)(base + 29360128);     //  3 MB
    u16*   Xh   = (u16*)(base + 32505856);     //  8 MB
    u16*   Qbh  = (u16*)(base + 40894464);     //  8 MB
    u16*   Qbl  = (u16*)(base + 49283072);     //  8 MB
    u16*   Kbh  = (u16*)(base + 57671680);     //  2 MB
    u16*   Kbl  = (u16*)(base + 59768832);     //  2 MB
    u16*   Vth  = (u16*)(base + 61865984);     //  2 MB
    u16*   Vtl  = (u16*)(base + 63963136);     //  2 MB
    u16*   AOh  = (u16*)(base + 66060288);     //  8 MB
    u16*   AOl  = (u16*)(base + 74448896);     //  8 MB
    u16*   FFh  = (u16*)(base + 82837504);     // 32 MB (end 116,391,936)

    // aliases (lifetime-checked):
    float* H2 = (float*)Qbh;   // 16 MB over Qbh+Qbl (Q dead post-attn)
    u16*   Yh = Kbh;           //  8 MB over Kbh..Vtl (K/V dead post-attn)
    u16*   Yl = AOh;           //  8 MB over AOh (AO dead post-o-proj)

    // 0. all weight prep, one launch
    wprep_all_kernel<<<14848, 256, 0, stream>>>(
        q_w, k_w, v_w, o_w, gate_w, up_w, down_w,
        QKVT, OTh, OTl, GTh, UTh, DTh);

    // 1. x = rmsnorm(hidden, ln1) -> bf16
    rmsnorm_split_kernel<0><<<Mrows, 256, 0, stream>>>(hidden, ln1, Xh, nullptr);

    // 2. fused qkv projection + qknorm + rope + split + V-transpose
    qkv_fused_kernel<<<dim3(12, 32), 256, 0, stream>>>(
        Xh, QKVT, qn, kn, sinp, cosp, Qbh, Qbl, Kbh, Kbl, Vth, Vtl);

    // 3. MFMA flash attention v3 (r8 revert) -> AO bf16 hi/lo
    attn_mfma_kernel<<<Bsz * Gg * (Tseq / 16), 256, 0, stream>>>(
        Qbh, Qbl, Kbh, Kbl, Vth, Vtl, AOh, AOl);

    // 4. hidden2 = hidden + attn @ o_w  (split x split)
    mfma_gemm_kernel<1, 1, 1><<<dim3(8, 32), 256, 0, stream>>>(
        AOh, AOl, OTh, OTl, hidden, H2, Mrows, Dmod, 1024);

    // 5. y = rmsnorm(hidden2, ln2) -> bf16 hi/lo
    rmsnorm_split_kernel<1><<<Mrows, 256, 0, stream>>>(H2, ln2, Yh, Yl);

    // 6. ff = silu(y@gate_w) * (y@up_w) -> FF bf16  (128x64 tiles)
    mfma_gateup_kernel<<<dim3(Ff / 64, Mrows / 128), 256, 0, stream>>>(
        Yh, Yl, GTh, UTh, FFh, Mrows, Ff, 1024);

    // 7. out = hidden2 + ff @ down_w
    mfma_gemm_kernel<0, 0, 1><<<dim3(8, 32), 256, 0, stream>>>(
        FFh, nullptr, DTh, nullptr, H2, out, Mrows, Dmod, 4096);
}